// Round 7
// baseline (221.160 us; speedup 1.0000x reference)
//
#include <hip/hip_runtime.h>
#include <cmath>

// ---------------------------------------------------------------------------
// DistanceAwareMultiheadAttention  (N=1536, E=49152, D=512, H=8, DH=64)
//
// Round 7:
//  - delta_k: revolution-domain hw v_sin/v_cos (the old __sincosf was
//    libm-precise with Payne-Hanek reduction at x~724 rad -> the hidden whale)
//  - maxpool tail: combine_mp does ordered-uint atomicMax into 512 slots
//    (deterministic; drops the 1-block latency-bound mp2)
//  - qkvm: kc loop software-pipelined (2-step ping-pong frag loads)
//  - flash: SPLITS 4->6 (4608 blocks, up to 16 waves/CU), workspace relaid
//    so the 18.9 MB Opart overlays Q/K/V + feat/W packs + rel (all dead)
// ---------------------------------------------------------------------------

constexpr int Nn  = 1536;
constexpr int Dd  = 512;
constexpr int Hh  = 8;
constexpr int DHd = 64;
constexpr int SPLITS = 6;
constexpr float SCALE_F = 362.03867196751236f;   // 256*sqrt(2)
constexpr float M0 = 8.0f;                       // fixed softmax exp offset

typedef float f4 __attribute__((ext_vector_type(4)));
typedef int   i4 __attribute__((ext_vector_type(4)));
typedef __attribute__((ext_vector_type(4))) float f32x4;
typedef __attribute__((ext_vector_type(8))) short bf16x8;

__device__ inline unsigned short bf16_rne(float x) {
    unsigned u = __float_as_uint(x);
    unsigned r = u + 0x7fff + ((u >> 16) & 1);
    return (unsigned short)(r >> 16);
}
__device__ inline float bf16_tof(unsigned short h) {
    return __uint_as_float(((unsigned)h) << 16);
}
// monotone float -> uint order encoding (for atomicMax over floats)
__device__ inline unsigned f2ord(float x) {
    unsigned b = __float_as_uint(x);
    return (b & 0x80000000u) ? ~b : (b | 0x80000000u);
}

// ------------- pack feat / W into MFMA fragment order (hi/lo bf16) ----------
__global__ __launch_bounds__(256) void pack_fw_k(
    const float* __restrict__ feat,
    const float* __restrict__ Wq, const float* __restrict__ Wk, const float* __restrict__ Wv,
    unsigned short* __restrict__ pFh, unsigned short* __restrict__ pFl,
    unsigned short* __restrict__ pWh, unsigned short* __restrict__ pWl)
{
    int tg = blockIdx.x * 256 + threadIdx.x;   // 98304 per type
    int type = blockIdx.y;                     // 0 = feat, 1 = W(all 3)
    int L = tg & 63;
    int kc = (tg >> 6) & 15;
    int t10 = tg >> 10;                        // 0..95
    const float* src;
    unsigned short *oh, *ol;
    int row, col;
    if (type == 0) {
        src = feat; oh = pFh; ol = pFl;
        row = t10 * 16 + (L & 15);
        col = kc * 32 + (L >> 4) * 8;
    } else {
        int z = t10 >> 5, nt = t10 & 31;
        src = (z == 0) ? Wq : (z == 1) ? Wk : Wv;
        oh = pWh; ol = pWl;
        row = nt * 16 + (L & 15);
        col = kc * 32 + (L >> 4) * 8;
    }
    f4 a = *(const f4*)(src + (size_t)row * Dd + col);
    f4 b = *(const f4*)(src + (size_t)row * Dd + col + 4);
    float x[8];
    #pragma unroll
    for (int j = 0; j < 4; ++j) { x[j] = a[j]; x[4 + j] = b[j]; }
    unsigned short hs[8], ls[8];
    #pragma unroll
    for (int j = 0; j < 8; ++j) {
        hs[j] = bf16_rne(x[j]);
        ls[j] = bf16_rne(x[j] - bf16_tof(hs[j]));
    }
    *(bf16x8*)(oh + (size_t)tg * 8) = *(bf16x8*)hs;
    *(bf16x8*)(ol + (size_t)tg * 8) = *(bf16x8*)ls;
}

// ------------------ QKV projection, MFMA, kc-pipelined ----------------------
__global__ __launch_bounds__(256) void qkvm_k(
    const unsigned short* __restrict__ pFh, const unsigned short* __restrict__ pFl,
    const unsigned short* __restrict__ pWh, const unsigned short* __restrict__ pWl,
    const float* __restrict__ bq, const float* __restrict__ bk, const float* __restrict__ bv,
    float* __restrict__ Qo, float* __restrict__ Ko, float* __restrict__ Vo)
{
    const int z = blockIdx.z;
    const float* __restrict__ bias = (z == 0) ? bq : (z == 1) ? bk : bv;
    float* __restrict__ outp       = (z == 0) ? Qo : (z == 1) ? Ko : Vo;
    const int tid = threadIdx.x;
    const int L = tid & 63, wv = tid >> 6;
    const int l15 = L & 15, quad = L >> 4;
    const int mt0 = blockIdx.y * 4 + (wv & 1) * 2;
    const int nt0 = blockIdx.x * 4 + (wv >> 1) * 2;

    f32x4 acc[2][2];
    #pragma unroll
    for (int i = 0; i < 2; ++i)
        #pragma unroll
        for (int j = 0; j < 2; ++j) acc[i][j] = (f32x4){0.f, 0.f, 0.f, 0.f};

    bf16x8 AH[2][2], AL[2][2], BH[2][2], BL[2][2];   // [buf][i]
    auto loadset = [&](int buf, int kc) {
        #pragma unroll
        for (int i = 0; i < 2; ++i) {
            size_t ao = ((size_t)((mt0 + i) * 16 + kc)) * 512 + L * 8;
            AH[buf][i] = *(const bf16x8*)(pFh + ao);
            AL[buf][i] = *(const bf16x8*)(pFl + ao);
            size_t bo = ((size_t)((z * 32 + nt0 + i) * 16 + kc)) * 512 + L * 8;
            BH[buf][i] = *(const bf16x8*)(pWh + bo);
            BL[buf][i] = *(const bf16x8*)(pWl + bo);
        }
    };
    auto mfmaset = [&](int buf) {
        #pragma unroll
        for (int i = 0; i < 2; ++i)
            #pragma unroll
            for (int j = 0; j < 2; ++j) {
                f32x4 a = acc[i][j];
                a = __builtin_amdgcn_mfma_f32_16x16x32_bf16(AH[buf][i], BH[buf][j], a, 0, 0, 0);
                a = __builtin_amdgcn_mfma_f32_16x16x32_bf16(AH[buf][i], BL[buf][j], a, 0, 0, 0);
                a = __builtin_amdgcn_mfma_f32_16x16x32_bf16(AL[buf][i], BH[buf][j], a, 0, 0, 0);
                a = __builtin_amdgcn_mfma_f32_16x16x32_bf16(AL[buf][i], BL[buf][j], a, 0, 0, 0);
                acc[i][j] = a;
            }
    };

    loadset(0, 0);
    #pragma unroll
    for (int kc = 0; kc < 16; kc += 2) {
        loadset(1, kc + 1);
        mfmaset(0);
        if (kc + 2 < 16) loadset(0, kc + 2);
        mfmaset(1);
    }

    #pragma unroll
    for (int i = 0; i < 2; ++i) {
        int row0 = (mt0 + i) * 16 + quad * 4;
        #pragma unroll
        for (int j = 0; j < 2; ++j) {
            int col = (nt0 + j) * 16 + l15;
            float b = bias[col];
            #pragma unroll
            for (int reg = 0; reg < 4; ++reg)
                outp[(size_t)(row0 + reg) * Dd + col] = acc[i][j][reg] + b;
        }
    }
}

// -------------------- pack Q/K/V into MFMA fragment order -------------------
__global__ __launch_bounds__(256) void pack_k(
    const float* __restrict__ Q, const float* __restrict__ K, const float* __restrict__ V,
    unsigned short* __restrict__ pQh, unsigned short* __restrict__ pQl,
    unsigned short* __restrict__ pKh, unsigned short* __restrict__ pKl,
    unsigned short* __restrict__ pVh, unsigned short* __restrict__ pVl)
{
    int tg = blockIdx.x * 256 + threadIdx.x;   // 98304 per type
    int type = blockIdx.y;
    int L = tg & 63;
    float x[8];
    unsigned short* oh;
    unsigned short* ol;
    if (type < 2) {
        const float* src = type ? K : Q;
        oh = type ? pKh : pQh;
        ol = type ? pKl : pQl;
        int kc = (tg >> 6) & 1;
        int mt = (tg >> 7) % 96;
        int h  = (tg >> 7) / 96;
        int row = mt * 16 + (L & 15);
        int col = h * 64 + kc * 32 + (L >> 4) * 8;
        f4 a = *(const f4*)(src + (size_t)row * Dd + col);
        f4 b = *(const f4*)(src + (size_t)row * Dd + col + 4);
        float sc = type ? 1.0f : 0.25f;
        #pragma unroll
        for (int j = 0; j < 4; ++j) { x[j] = a[j] * sc; x[4 + j] = b[j] * sc; }
    } else {
        oh = pVh; ol = pVl;
        int dt = (tg >> 6) & 3;
        int rc = (tg >> 8) % 48;
        int h  = (tg >> 8) / 48;
        int col  = h * 64 + dt * 16 + (L & 15);
        int row0 = rc * 32 + (L >> 4) * 8;
        #pragma unroll
        for (int j = 0; j < 8; ++j) x[j] = V[(size_t)(row0 + j) * Dd + col];
    }
    unsigned short hs[8], ls[8];
    #pragma unroll
    for (int j = 0; j < 8; ++j) {
        hs[j] = bf16_rne(x[j]);
        ls[j] = bf16_rne(x[j] - bf16_tof(hs[j]));
    }
    *(bf16x8*)(oh + (size_t)tg * 8) = *(bf16x8*)hs;
    *(bf16x8*)(ol + (size_t)tg * 8) = *(bf16x8*)ls;
}

// ---------------- rel / eid init (vectorized) + ordmax init -----------------
__global__ __launch_bounds__(256) void init_rel_k(float* __restrict__ rel,
                                                  int* __restrict__ eid,
                                                  unsigned* __restrict__ ordmax)
{
    size_t idx = (size_t)blockIdx.x * 256 + threadIdx.x;
    size_t i = idx * 4;
    if (i < (size_t)Nn * Nn) {
        *(f4*)(rel + i) = (f4){0.f, 0.f, 0.f, 0.f};
        *(i4*)(eid + i) = (i4){-1, -1, -1, -1};
    }
    if (idx < 128) {
        #pragma unroll
        for (int c = 0; c < 4; ++c) ordmax[idx * 4 + c] = 0x007FFFFFu;  // encode(-inf)
    }
}

// ----------------- scatter (with inline int64/int32 detect) -----------------
__global__ __launch_bounds__(256) void scatter_k(
    const int* __restrict__ raw, const float* __restrict__ attr,
    float* __restrict__ rel, int* __restrict__ eid, int* __restrict__ idxn, int E)
{
    int e = blockIdx.x * 256 + threadIdx.x;
    if (e >= E) return;
    int acc = 0;
    #pragma unroll
    for (int i = 0; i < 16; ++i) acc |= raw[2 * i + 1];
    int s, t;
    if (acc == 0) { s = raw[2 * e]; t = raw[2 * (E + e)]; }   // int64 low words
    else          { s = raw[e];     t = raw[E + e]; }          // plain int32
    idxn[e] = s; idxn[E + e] = t;
    size_t off = (size_t)s * Nn + t;
    atomicAdd(rel + off, attr[e] * SCALE_F);
    eid[off] = e;
}

// ------------------ odd-index sums (PE at rel==0 constants) -----------------
__global__ void oddsum_k(const float* __restrict__ Q, const float* __restrict__ K,
                         float* __restrict__ qodd, float* __restrict__ kodd,
                         float* __restrict__ koddT)
{
    int t = blockIdx.x * 256 + threadIdx.x;
    if (t >= 2 * Nn * Hh) return;
    const float* src = (t < Nn * Hh) ? Q : K;
    int i = (t < Nn * Hh) ? t : t - Nn * Hh;
    int n = i >> 3, h = i & 7;
    const float* row = src + (size_t)n * Dd + h * DHd;
    float s = 0.f;
    #pragma unroll
    for (int ii = 0; ii < 32; ++ii) s += row[2 * ii + 1];
    if (t < Nn * Hh) qodd[i] = s;
    else { kodd[i] = s; koddT[h * Nn + n] = 0.125f * s; }
}

// ------------------- per-edge, per-head logit corrections -------------------
// hw sin/cos in revolution domain: rev = x*div/(2pi), fract, v_sin/v_cos.
// div/(2pi) built from hw exp2 (no libm, no folding dependence).
__global__ __launch_bounds__(256) void delta_k(
    const int* __restrict__ idxn, const float* __restrict__ rel,
    const float* __restrict__ Q, const float* __restrict__ K,
    const float* __restrict__ qodd, const float* __restrict__ kodd,
    float* __restrict__ delta8, int E)
{
    int t = blockIdx.x * 256 + threadIdx.x;
    if (t >= E * Hh) return;
    int e = t >> 3, h = t & 7;
    int qi = idxn[e], ri = idxn[E + e];
    float x = rel[(size_t)qi * Nn + ri];
    const float* qrow = Q + (size_t)qi * Dd + h * DHd;
    const float* krow = K + (size_t)ri * Dd + h * DHd;
    float acc = 0.f;
    #pragma unroll
    for (int i = 0; i < 32; i += 2) {
        // dd = (1/2pi) * 10000^(-i/32)   via hw exp2
        float dd0 = 0.15915494309189535f * __builtin_amdgcn_exp2f(-0.4152410118609203f * (float)i);
        float dd1 = 0.15915494309189535f * __builtin_amdgcn_exp2f(-0.4152410118609203f * (float)(i + 1));
        float r0 = x * dd0; r0 -= floorf(r0);
        float r1 = x * dd1; r1 -= floorf(r1);
        float s0 = __builtin_amdgcn_sinf(r0), c0 = __builtin_amdgcn_cosf(r0);
        float s1 = __builtin_amdgcn_sinf(r1), c1 = __builtin_amdgcn_cosf(r1);
        f4 q4 = *(const f4*)(qrow + 2 * i);
        f4 k4 = *(const f4*)(krow + 2 * i);
        acc += (q4[0] + k4[0]) * s0 + (q4[1] + k4[1]) * c0
             + (q4[2] + k4[2]) * s1 + (q4[3] + k4[3]) * c1;
    }
    delta8[(size_t)e * Hh + h] = 0.125f * (acc - qodd[qi * Hh + h] - kodd[ri * Hh + h]);
}

// ---------------- flash attention, no-max softmax + K dbuf ------------------
__global__ __launch_bounds__(64, 4) void flash6_k(
    const unsigned short* __restrict__ pQh, const unsigned short* __restrict__ pQl,
    const unsigned short* __restrict__ pKh, const unsigned short* __restrict__ pKl,
    const unsigned short* __restrict__ pVh, const unsigned short* __restrict__ pVl,
    const int* __restrict__ eid, const float* __restrict__ delta8,
    const float* __restrict__ koddT,
    float* __restrict__ Opart, float* __restrict__ Lpart)
{
    const int qt = blockIdx.x, h = blockIdx.y, s = blockIdx.z;
    const int L = threadIdx.x, quad = L >> 4, l15 = L & 15;
    const int q0 = qt * 16;
    __shared__ unsigned short phi[16][80];
    __shared__ unsigned short plo[16][80];

    bf16x8 qh[2], ql[2];
    #pragma unroll
    for (int kc = 0; kc < 2; ++kc) {
        size_t off = ((size_t)((h * 96 + qt) * 2 + kc)) * 512 + L * 8;
        qh[kc] = *(const bf16x8*)(pQh + off);
        ql[kc] = *(const bf16x8*)(pQl + off);
    }

    f32x4 O[4];
    float lsum[4];
    #pragma unroll
    for (int r = 0; r < 4; ++r) { lsum[r] = 0.f; O[r] = (f32x4){0.f, 0.f, 0.f, 0.f}; }

    const int NT = 24 / SPLITS;         // 4 r-tiles per split
    const int Tbase = s * NT;

    // ---- K frag double buffer: preload tile 0 ----
    bf16x8 kh0[4], kh1[4], kl0[4], kl1[4];
    {
        const int r0 = Tbase * 64;
        #pragma unroll
        for (int nt = 0; nt < 4; ++nt) {
            size_t b0 = ((size_t)((h * 96 + (r0 >> 4) + nt) * 2)) * 512 + L * 8;
            kh0[nt] = *(const bf16x8*)(pKh + b0);
            kh1[nt] = *(const bf16x8*)(pKh + b0 + 512);
            kl0[nt] = *(const bf16x8*)(pKl + b0);
            kl1[nt] = *(const bf16x8*)(pKl + b0 + 512);
        }
    }

    // ---- meta for tile 0 ----
    float kvcur[4], dcur[16];
    {
        const int r0 = Tbase * 64;
        int ecur[16];
        #pragma unroll
        for (int nt = 0; nt < 4; ++nt) {
            kvcur[nt] = koddT[h * Nn + r0 + nt * 16 + l15];
            #pragma unroll
            for (int reg = 0; reg < 4; ++reg)
                ecur[nt * 4 + reg] = eid[(size_t)(q0 + quad * 4 + reg) * Nn + r0 + nt * 16 + l15];
        }
        #pragma unroll
        for (int i = 0; i < 16; ++i) {
            int e = ecur[i];
            float d = delta8[(size_t)(e < 0 ? 0 : e) * Hh + h];
            dcur[i] = (e >= 0) ? d : 0.f;
        }
    }

    for (int T = 0; T < NT; ++T) {
        const int r0 = (Tbase + T) * 64;
        const bool more = (T + 1 < NT);

        // ---- prefetch next tile's eid + koddT ----
        int   enxt[16];
        float kvnxt[4];
        if (more) {
            const int r1 = r0 + 64;
            #pragma unroll
            for (int nt = 0; nt < 4; ++nt) {
                kvnxt[nt] = koddT[h * Nn + r1 + nt * 16 + l15];
                #pragma unroll
                for (int reg = 0; reg < 4; ++reg)
                    enxt[nt * 4 + reg] = eid[(size_t)(q0 + quad * 4 + reg) * Nn + r1 + nt * 16 + l15];
            }
        }

        // ---- V loads for this tile (early issue; consumed after exp) ----
        bf16x8 vh0[4], vh1[4], vl0[4], vl1[4];
        #pragma unroll
        for (int dt = 0; dt < 4; ++dt) {
            size_t vb = ((size_t)((h * 48 + (r0 >> 5)) * 4 + dt)) * 512 + L * 8;
            vh0[dt] = *(const bf16x8*)(pVh + vb);
            vh1[dt] = *(const bf16x8*)(pVh + vb + 2048);
            vl0[dt] = *(const bf16x8*)(pVl + vb);
            vl1[dt] = *(const bf16x8*)(pVl + vb + 2048);
        }

        // ---- S = 0.25 * Q K^T from the current K buffer ----
        f32x4 S[4];
        #pragma unroll
        for (int nt = 0; nt < 4; ++nt) {
            f32x4 a = {0.f, 0.f, 0.f, 0.f};
            a = __builtin_amdgcn_mfma_f32_16x16x32_bf16(qh[0], kh0[nt], a, 0, 0, 0);
            a = __builtin_amdgcn_mfma_f32_16x16x32_bf16(qh[1], kh1[nt], a, 0, 0, 0);
            a = __builtin_amdgcn_mfma_f32_16x16x32_bf16(qh[0], kl0[nt], a, 0, 0, 0);
            a = __builtin_amdgcn_mfma_f32_16x16x32_bf16(qh[1], kl1[nt], a, 0, 0, 0);
            a = __builtin_amdgcn_mfma_f32_16x16x32_bf16(ql[0], kh0[nt], a, 0, 0, 0);
            a = __builtin_amdgcn_mfma_f32_16x16x32_bf16(ql[1], kh1[nt], a, 0, 0, 0);
            S[nt] = a;
        }

        // ---- refill K buffer for next tile (long issue->use distance) ----
        if (more) {
            const int r1 = r0 + 64;
            #pragma unroll
            for (int nt = 0; nt < 4; ++nt) {
                size_t b0 = ((size_t)((h * 96 + (r1 >> 4) + nt) * 2)) * 512 + L * 8;
                kh0[nt] = *(const bf16x8*)(pKh + b0);
                kh1[nt] = *(const bf16x8*)(pKh + b0 + 512);
                kl0[nt] = *(const bf16x8*)(pKl + b0);
                kl1[nt] = *(const bf16x8*)(pKl + b0 + 512);
            }
        }

        // ---- p = exp(logit - M0); accumulate row sums; pack to LDS ----
        #pragma unroll
        for (int reg = 0; reg < 4; ++reg) {
            float p[4];
            #pragma unroll
            for (int nt = 0; nt < 4; ++nt) {
                p[nt] = __expf(S[nt][reg] + kvcur[nt] + dcur[nt * 4 + reg] - M0);
                lsum[reg] += p[nt];
                unsigned short hi = bf16_rne(p[nt]);
                phi[quad * 4 + reg][nt * 16 + l15] = hi;
                plo[quad * 4 + reg][nt * 16 + l15] = bf16_rne(p[nt] - bf16_tof(hi));
            }
        }

        // ---- P A-frags from LDS (single wave: DS in-order, no barrier) ----
        bf16x8 ph[2], pl[2];
        #pragma unroll
        for (int kc2 = 0; kc2 < 2; ++kc2) {
            ph[kc2] = *(const bf16x8*)&phi[l15][kc2 * 32 + quad * 8];
            pl[kc2] = *(const bf16x8*)&plo[l15][kc2 * 32 + quad * 8];
        }

        // ---- O += P V ----
        #pragma unroll
        for (int dt = 0; dt < 4; ++dt) {
            f32x4 a = O[dt];
            a = __builtin_amdgcn_mfma_f32_16x16x32_bf16(ph[0], vh0[dt], a, 0, 0, 0);
            a = __builtin_amdgcn_mfma_f32_16x16x32_bf16(ph[1], vh1[dt], a, 0, 0, 0);
            a = __builtin_amdgcn_mfma_f32_16x16x32_bf16(ph[0], vl0[dt], a, 0, 0, 0);
            a = __builtin_amdgcn_mfma_f32_16x16x32_bf16(ph[1], vl1[dt], a, 0, 0, 0);
            a = __builtin_amdgcn_mfma_f32_16x16x32_bf16(pl[0], vh0[dt], a, 0, 0, 0);
            a = __builtin_amdgcn_mfma_f32_16x16x32_bf16(pl[1], vh1[dt], a, 0, 0, 0);
            O[dt] = a;
        }

        // ---- gather next tile's delta (eid prefetch has landed) ----
        if (more) {
            #pragma unroll
            for (int i = 0; i < 16; ++i) {
                int e = enxt[i];
                float d = delta8[(size_t)(e < 0 ? 0 : e) * Hh + h];
                dcur[i] = (e >= 0) ? d : 0.f;
            }
            #pragma unroll
            for (int nt = 0; nt < 4; ++nt) kvcur[nt] = kvnxt[nt];
        }
    }

    // ---- one deferred row-sum reduction (within each quad's 16 lanes) ----
    #pragma unroll
    for (int reg = 0; reg < 4; ++reg) {
        #pragma unroll
        for (int o = 1; o < 16; o <<= 1) lsum[reg] += __shfl_xor(lsum[reg], o);
    }

    // ---- store partials ----
    #pragma unroll
    for (int dt = 0; dt < 4; ++dt)
        #pragma unroll
        for (int reg = 0; reg < 4; ++reg)
            Opart[((size_t)(s * Hh + h) * Nn + q0 + quad * 4 + reg) * 64 + dt * 16 + l15] = O[dt][reg];
    if (l15 == 0) {
        #pragma unroll
        for (int reg = 0; reg < 4; ++reg)
            Lpart[(size_t)(s * Hh + h) * Nn + q0 + quad * 4 + reg] = lsum[reg];
    }
}

// ------- split-K combine + maxpool via ordered-uint atomicMax (512 slots) ---
__global__ __launch_bounds__(256) void combine_mp_k(
    const float* __restrict__ Opart, const float* __restrict__ Lpart,
    unsigned* __restrict__ ordmax)
{
    const int b = blockIdx.x;
    const int t = threadIdx.x;
    const int cg = (t & 127) * 4;
    const int h = cg >> 6, d = cg & 63;
    const int rh = t >> 7;
    f4 mx = {-3.0e38f, -3.0e38f, -3.0e38f, -3.0e38f};
    for (int r = 0; r < 8; ++r) {
        int q = b * 16 + rh * 8 + r;
        float l = 0.f;
        f4 o = {0.f, 0.f, 0.f, 0.f};
        #pragma unroll
        for (int s2 = 0; s2 < SPLITS; ++s2) {
            l += Lpart[(size_t)(s2 * Hh + h) * Nn + q];
            f4 ov = *(const f4*)(Opart + ((size_t)(s2 * Hh + h) * Nn + q) * 64 + d);
            #pragma unroll
            for (int c = 0; c < 4; ++c) o[c] += ov[c];
        }
        float inv = 1.0f / l;
        #pragma unroll
        for (int c = 0; c < 4; ++c) mx[c] = fmaxf(mx[c], o[c] * inv);
    }
    #pragma unroll
    for (int c = 0; c < 4; ++c) atomicMax(&ordmax[cg + c], f2ord(mx[c]));
}

__global__ void decode_k(const unsigned* __restrict__ ordmax, float* __restrict__ outp)
{
    int t = blockIdx.x * 256 + threadIdx.x;
    if (t >= Dd) return;
    unsigned u = ordmax[t];
    outp[t] = (u & 0x80000000u) ? __uint_as_float(u ^ 0x80000000u) : __uint_as_float(~u);
}

// ---------------------------------------------------------------------------
extern "C" void kernel_launch(void* const* d_in, const int* in_sizes, int n_in,
                              void* d_out, int out_size, void* d_ws, size_t ws_size,
                              hipStream_t stream)
{
    const float* feat   = (const float*)d_in[0];
    const int*   rawidx = (const int*)d_in[1];
    const float* attr   = (const float*)d_in[2];
    const float* Wq = (const float*)d_in[4];
    const float* bq = (const float*)d_in[5];
    const float* Wk = (const float*)d_in[6];
    const float* bk = (const float*)d_in[7];
    const float* Wv = (const float*)d_in[8];
    const float* bv = (const float*)d_in[9];
    float* outp = (float*)d_out;
    const int E = in_sizes[2];

    const size_t ND_ = (size_t)Nn * Dd;            // 786432
    const size_t NN_ = (size_t)Nn * Nn;            // 2359296
    const size_t PK_ = (size_t)Hh * 96 * 2 * 512;  // 786432 bf16 per pack array
    // Layout (so Opart = 6*8*1536*64 floats = 18.9 MB fits in the dead-at-flash
    // prefix Q,K,V + feat/W packs + rel = 25.2 MB; eid onwards stays live):
    float* ws    = (float*)d_ws;
    float* Q     = ws;                    // 786432 f
    float* K     = Q + ND_;               // 786432 f
    float* V     = K + ND_;               // 786432 f
    unsigned short* pFh = (unsigned short*)(V + ND_);   // 4 x 786432 shorts
    unsigned short* pFl = pFh + PK_;
    unsigned short* pWh = pFl + PK_;
    unsigned short* pWl = pWh + PK_;
    float* rel   = (float*)(pWl + PK_);   // 2359296 f
    int*   eid   = (int*)(rel + NN_);     // 2359296 i  (live through flash)
    float* delta8 = (float*)(eid + NN_);  // E*Hh
    float* qodd  = delta8 + (size_t)E * Hh;
    float* kodd  = qodd + (size_t)Nn * Hh;
    float* koddT = kodd + (size_t)Nn * Hh;
    int*   idxn  = (int*)(koddT + (size_t)Nn * Hh);
    unsigned short* pQh = (unsigned short*)(idxn + 2 * E);
    unsigned short* pQl = pQh + PK_;
    unsigned short* pKh = pQl + PK_;
    unsigned short* pKl = pKh + PK_;
    unsigned short* pVh = pKl + PK_;
    unsigned short* pVl = pVh + PK_;
    float* Lpart = (float*)(pVl + PK_);                  // SPLITS*Hh*Nn
    unsigned* ordmax = (unsigned*)(Lpart + (size_t)SPLITS * Hh * Nn);  // 512
    float* Opart = ws;   // overlays Q..rel head (all dead by flash time)

    pack_fw_k<<<dim3(384, 2), 256, 0, stream>>>(feat, Wq, Wk, Wv, pFh, pFl, pWh, pWl);
    qkvm_k<<<dim3(8, 24, 3), 256, 0, stream>>>(pFh, pFl, pWh, pWl, bq, bk, bv, Q, K, V);
    init_rel_k<<<(int)((NN_ / 4 + 255) / 256), 256, 0, stream>>>(rel, eid, ordmax);
    scatter_k<<<(E + 255) / 256, 256, 0, stream>>>(rawidx, attr, rel, eid, idxn, E);
    oddsum_k<<<(2 * Nn * Hh + 255) / 256, 256, 0, stream>>>(Q, K, qodd, kodd, koddT);
    delta_k<<<(E * Hh + 255) / 256, 256, 0, stream>>>(idxn, rel, Q, K, qodd, kodd, delta8, E);
    pack_k<<<dim3(384, 3), 256, 0, stream>>>(Q, K, V, pQh, pQl, pKh, pKl, pVh, pVl);
    flash6_k<<<dim3(96, 8, SPLITS), 64, 0, stream>>>(pQh, pQl, pKh, pKl, pVh, pVl,
                                                     eid, delta8, koddT, Opart, Lpart);
    combine_mp_k<<<96, 256, 0, stream>>>(Opart, Lpart, ordmax);
    decode_k<<<(Dd + 255) / 256, 256, 0, stream>>>(ordmax, outp);
}

// Round 8
// 196.673 us; speedup vs baseline: 1.1245x; 1.1245x over previous
//
#include <hip/hip_runtime.h>
#include <cmath>

// ---------------------------------------------------------------------------
// DistanceAwareMultiheadAttention  (N=1536, E=49152, D=512, H=8, DH=64)
//
// Round 8:
//  - REVERT flash to round-6 flash5 exactly (SPLITS=4, launch_bounds(64,3)):
//    round 7's (64,4) clamp pinned VGPR to 64 -> scratch spills (+35MB HBM
//    traffic, 44.5 -> 62.7us). Lesson: never buy TLP with spills.
//  - pack_k ELIMINATED: Q/K/V fragment packing fused into qkvm epilogue via
//    per-wave 32x32 LDS transpose (wave C-tile == 2 Q/K frags + 2 V frags).
//    V f32 is never materialized. Saves ~25MB traffic + a launch.
//  - keep: atomicMax maxpool tail, pipelined qkvm kc loop, libm-free delta.
// ---------------------------------------------------------------------------

constexpr int Nn  = 1536;
constexpr int Dd  = 512;
constexpr int Hh  = 8;
constexpr int DHd = 64;
constexpr int SPLITS = 4;
constexpr float SCALE_F = 362.03867196751236f;   // 256*sqrt(2)
constexpr float M0 = 8.0f;                       // fixed softmax exp offset

typedef float f4 __attribute__((ext_vector_type(4)));
typedef int   i4 __attribute__((ext_vector_type(4)));
typedef __attribute__((ext_vector_type(4))) float f32x4;
typedef __attribute__((ext_vector_type(8))) short bf16x8;

__device__ inline unsigned short bf16_rne(float x) {
    unsigned u = __float_as_uint(x);
    unsigned r = u + 0x7fff + ((u >> 16) & 1);
    return (unsigned short)(r >> 16);
}
__device__ inline float bf16_tof(unsigned short h) {
    return __uint_as_float(((unsigned)h) << 16);
}
// monotone float -> uint order encoding (for atomicMax over floats)
__device__ inline unsigned f2ord(float x) {
    unsigned b = __float_as_uint(x);
    return (b & 0x80000000u) ? ~b : (b | 0x80000000u);
}

// ------------- pack feat / W into MFMA fragment order (hi/lo bf16) ----------
__global__ __launch_bounds__(256) void pack_fw_k(
    const float* __restrict__ feat,
    const float* __restrict__ Wq, const float* __restrict__ Wk, const float* __restrict__ Wv,
    unsigned short* __restrict__ pFh, unsigned short* __restrict__ pFl,
    unsigned short* __restrict__ pWh, unsigned short* __restrict__ pWl)
{
    int tg = blockIdx.x * 256 + threadIdx.x;   // 98304 per type
    int type = blockIdx.y;                     // 0 = feat, 1 = W(all 3)
    int L = tg & 63;
    int kc = (tg >> 6) & 15;
    int t10 = tg >> 10;                        // 0..95
    const float* src;
    unsigned short *oh, *ol;
    int row, col;
    if (type == 0) {
        src = feat; oh = pFh; ol = pFl;
        row = t10 * 16 + (L & 15);
        col = kc * 32 + (L >> 4) * 8;
    } else {
        int z = t10 >> 5, nt = t10 & 31;
        src = (z == 0) ? Wq : (z == 1) ? Wk : Wv;
        oh = pWh; ol = pWl;
        row = nt * 16 + (L & 15);
        col = kc * 32 + (L >> 4) * 8;
    }
    f4 a = *(const f4*)(src + (size_t)row * Dd + col);
    f4 b = *(const f4*)(src + (size_t)row * Dd + col + 4);
    float x[8];
    #pragma unroll
    for (int j = 0; j < 4; ++j) { x[j] = a[j]; x[4 + j] = b[j]; }
    unsigned short hs[8], ls[8];
    #pragma unroll
    for (int j = 0; j < 8; ++j) {
        hs[j] = bf16_rne(x[j]);
        ls[j] = bf16_rne(x[j] - bf16_tof(hs[j]));
    }
    *(bf16x8*)(oh + (size_t)tg * 8) = *(bf16x8*)hs;
    *(bf16x8*)(ol + (size_t)tg * 8) = *(bf16x8*)ls;
}

// --------- QKV projection, MFMA, kc-pipelined, fused fragment pack ----------
// grid (8,24,3) block 256 = 4 waves; wave = 32 rows x 32 cols.
// Epilogue: per-wave LDS transpose of the 32x32 tile, then:
//   z<2: f32 Q/K store + Q/K A-frag pack (Q scaled 0.25)
//   z=2: V B-frag pack only (V f32 never materialized)
__global__ __launch_bounds__(256) void qkvm_k(
    const unsigned short* __restrict__ pFh, const unsigned short* __restrict__ pFl,
    const unsigned short* __restrict__ pWh, const unsigned short* __restrict__ pWl,
    const float* __restrict__ bq, const float* __restrict__ bk, const float* __restrict__ bv,
    float* __restrict__ Qo, float* __restrict__ Ko,
    unsigned short* __restrict__ pQh, unsigned short* __restrict__ pQl,
    unsigned short* __restrict__ pKh, unsigned short* __restrict__ pKl,
    unsigned short* __restrict__ pVh, unsigned short* __restrict__ pVl)
{
    const int z = blockIdx.z;
    const float* __restrict__ bias = (z == 0) ? bq : (z == 1) ? bk : bv;
    const int tid = threadIdx.x;
    const int L = tid & 63, wv = tid >> 6;
    const int l15 = L & 15, quad = L >> 4;
    const int mt0 = blockIdx.y * 4 + (wv & 1) * 2;
    const int nt0 = blockIdx.x * 4 + (wv >> 1) * 2;
    __shared__ float lds[4][32][33];

    f32x4 acc[2][2];
    #pragma unroll
    for (int i = 0; i < 2; ++i)
        #pragma unroll
        for (int j = 0; j < 2; ++j) acc[i][j] = (f32x4){0.f, 0.f, 0.f, 0.f};

    bf16x8 AH[2][2], AL[2][2], BH[2][2], BL[2][2];   // [buf][i]
    auto loadset = [&](int buf, int kc) {
        #pragma unroll
        for (int i = 0; i < 2; ++i) {
            size_t ao = ((size_t)((mt0 + i) * 16 + kc)) * 512 + L * 8;
            AH[buf][i] = *(const bf16x8*)(pFh + ao);
            AL[buf][i] = *(const bf16x8*)(pFl + ao);
            size_t bo = ((size_t)((z * 32 + nt0 + i) * 16 + kc)) * 512 + L * 8;
            BH[buf][i] = *(const bf16x8*)(pWh + bo);
            BL[buf][i] = *(const bf16x8*)(pWl + bo);
        }
    };
    auto mfmaset = [&](int buf) {
        #pragma unroll
        for (int i = 0; i < 2; ++i)
            #pragma unroll
            for (int j = 0; j < 2; ++j) {
                f32x4 a = acc[i][j];
                a = __builtin_amdgcn_mfma_f32_16x16x32_bf16(AH[buf][i], BH[buf][j], a, 0, 0, 0);
                a = __builtin_amdgcn_mfma_f32_16x16x32_bf16(AH[buf][i], BL[buf][j], a, 0, 0, 0);
                a = __builtin_amdgcn_mfma_f32_16x16x32_bf16(AL[buf][i], BH[buf][j], a, 0, 0, 0);
                a = __builtin_amdgcn_mfma_f32_16x16x32_bf16(AL[buf][i], BL[buf][j], a, 0, 0, 0);
                acc[i][j] = a;
            }
    };

    loadset(0, 0);
    #pragma unroll
    for (int kc = 0; kc < 16; kc += 2) {
        loadset(1, kc + 1);
        mfmaset(0);
        if (kc + 2 < 16) loadset(0, kc + 2);
        mfmaset(1);
    }

    // ---- epilogue: bias, optional f32 store, LDS stage ----
    float o_[2][2][4];
    #pragma unroll
    for (int i = 0; i < 2; ++i)
        #pragma unroll
        for (int j = 0; j < 2; ++j) {
            float b = bias[(nt0 + j) * 16 + l15];
            #pragma unroll
            for (int reg = 0; reg < 4; ++reg) o_[i][j][reg] = acc[i][j][reg] + b;
        }
    if (z < 2) {
        float* __restrict__ outp = (z == 0) ? Qo : Ko;
        #pragma unroll
        for (int i = 0; i < 2; ++i) {
            int row0 = (mt0 + i) * 16 + quad * 4;
            #pragma unroll
            for (int j = 0; j < 2; ++j) {
                int col = (nt0 + j) * 16 + l15;
                #pragma unroll
                for (int reg = 0; reg < 4; ++reg)
                    outp[(size_t)(row0 + reg) * Dd + col] = o_[i][j][reg];
            }
        }
    }
    #pragma unroll
    for (int i = 0; i < 2; ++i)
        #pragma unroll
        for (int j = 0; j < 2; ++j)
            #pragma unroll
            for (int reg = 0; reg < 4; ++reg)
                lds[wv][i * 16 + quad * 4 + reg][j * 16 + l15] = o_[i][j][reg];
    // single-wave LDS round trip: DS pipe is in-order per wave, no barrier.

    const int h = blockIdx.x;   // cols [h*64, h*64+64) == head h
    if (z < 2) {
        unsigned short* __restrict__ oh = z ? pKh : pQh;
        unsigned short* __restrict__ ol = z ? pKl : pQl;
        const int kc = wv >> 1;                 // 32-col half of the head
        const float sc = z ? 1.0f : 0.25f;      // Q pre-scaled (exact pow2)
        #pragma unroll
        for (int i = 0; i < 2; ++i) {
            float x[8]; unsigned short hs[8], ls[8];
            #pragma unroll
            for (int j2 = 0; j2 < 8; ++j2)
                x[j2] = lds[wv][i * 16 + l15][quad * 8 + j2] * sc;
            #pragma unroll
            for (int j2 = 0; j2 < 8; ++j2) {
                hs[j2] = bf16_rne(x[j2]);
                ls[j2] = bf16_rne(x[j2] - bf16_tof(hs[j2]));
            }
            size_t off = ((size_t)((h * 96 + mt0 + i) * 2 + kc)) * 512 + L * 8;
            *(bf16x8*)(oh + off) = *(bf16x8*)hs;
            *(bf16x8*)(ol + off) = *(bf16x8*)ls;
        }
    } else {
        const int rc = blockIdx.y * 2 + (wv & 1);   // 32-row chunk
        #pragma unroll
        for (int dtl = 0; dtl < 2; ++dtl) {
            int dt = (wv >> 1) * 2 + dtl;           // 16-col dout tile
            float x[8]; unsigned short hs[8], ls[8];
            #pragma unroll
            for (int j2 = 0; j2 < 8; ++j2)
                x[j2] = lds[wv][quad * 8 + j2][dtl * 16 + l15];
            #pragma unroll
            for (int j2 = 0; j2 < 8; ++j2) {
                hs[j2] = bf16_rne(x[j2]);
                ls[j2] = bf16_rne(x[j2] - bf16_tof(hs[j2]));
            }
            size_t off = ((size_t)((h * 48 + rc) * 4 + dt)) * 512 + L * 8;
            *(bf16x8*)(pVh + off) = *(bf16x8*)hs;
            *(bf16x8*)(pVl + off) = *(bf16x8*)ls;
        }
    }
}

// ---------------- rel / eid init (vectorized) + ordmax init -----------------
__global__ __launch_bounds__(256) void init_rel_k(float* __restrict__ rel,
                                                  int* __restrict__ eid,
                                                  unsigned* __restrict__ ordmax)
{
    size_t idx = (size_t)blockIdx.x * 256 + threadIdx.x;
    size_t i = idx * 4;
    if (i < (size_t)Nn * Nn) {
        *(f4*)(rel + i) = (f4){0.f, 0.f, 0.f, 0.f};
        *(i4*)(eid + i) = (i4){-1, -1, -1, -1};
    }
    if (idx < 128) {
        #pragma unroll
        for (int c = 0; c < 4; ++c) ordmax[idx * 4 + c] = 0x007FFFFFu;  // encode(-inf)
    }
}

// ----------------- scatter (with inline int64/int32 detect) -----------------
__global__ __launch_bounds__(256) void scatter_k(
    const int* __restrict__ raw, const float* __restrict__ attr,
    float* __restrict__ rel, int* __restrict__ eid, int* __restrict__ idxn, int E)
{
    int e = blockIdx.x * 256 + threadIdx.x;
    if (e >= E) return;
    int acc = 0;
    #pragma unroll
    for (int i = 0; i < 16; ++i) acc |= raw[2 * i + 1];
    int s, t;
    if (acc == 0) { s = raw[2 * e]; t = raw[2 * (E + e)]; }   // int64 low words
    else          { s = raw[e];     t = raw[E + e]; }          // plain int32
    idxn[e] = s; idxn[E + e] = t;
    size_t off = (size_t)s * Nn + t;
    atomicAdd(rel + off, attr[e] * SCALE_F);
    eid[off] = e;
}

// ------------------ odd-index sums (PE at rel==0 constants) -----------------
__global__ void oddsum_k(const float* __restrict__ Q, const float* __restrict__ K,
                         float* __restrict__ qodd, float* __restrict__ kodd,
                         float* __restrict__ koddT)
{
    int t = blockIdx.x * 256 + threadIdx.x;
    if (t >= 2 * Nn * Hh) return;
    const float* src = (t < Nn * Hh) ? Q : K;
    int i = (t < Nn * Hh) ? t : t - Nn * Hh;
    int n = i >> 3, h = i & 7;
    const float* row = src + (size_t)n * Dd + h * DHd;
    float s = 0.f;
    #pragma unroll
    for (int ii = 0; ii < 32; ++ii) s += row[2 * ii + 1];
    if (t < Nn * Hh) qodd[i] = s;
    else { kodd[i] = s; koddT[h * Nn + n] = 0.125f * s; }
}

// ------------------- per-edge, per-head logit corrections -------------------
// hw sin/cos in revolution domain (libm-free).
__global__ __launch_bounds__(256) void delta_k(
    const int* __restrict__ idxn, const float* __restrict__ rel,
    const float* __restrict__ Q, const float* __restrict__ K,
    const float* __restrict__ qodd, const float* __restrict__ kodd,
    float* __restrict__ delta8, int E)
{
    int t = blockIdx.x * 256 + threadIdx.x;
    if (t >= E * Hh) return;
    int e = t >> 3, h = t & 7;
    int qi = idxn[e], ri = idxn[E + e];
    float x = rel[(size_t)qi * Nn + ri];
    const float* qrow = Q + (size_t)qi * Dd + h * DHd;
    const float* krow = K + (size_t)ri * Dd + h * DHd;
    float acc = 0.f;
    #pragma unroll
    for (int i = 0; i < 32; i += 2) {
        float dd0 = 0.15915494309189535f * __builtin_amdgcn_exp2f(-0.4152410118609203f * (float)i);
        float dd1 = 0.15915494309189535f * __builtin_amdgcn_exp2f(-0.4152410118609203f * (float)(i + 1));
        float r0 = x * dd0; r0 -= floorf(r0);
        float r1 = x * dd1; r1 -= floorf(r1);
        float s0 = __builtin_amdgcn_sinf(r0), c0 = __builtin_amdgcn_cosf(r0);
        float s1 = __builtin_amdgcn_sinf(r1), c1 = __builtin_amdgcn_cosf(r1);
        f4 q4 = *(const f4*)(qrow + 2 * i);
        f4 k4 = *(const f4*)(krow + 2 * i);
        acc += (q4[0] + k4[0]) * s0 + (q4[1] + k4[1]) * c0
             + (q4[2] + k4[2]) * s1 + (q4[3] + k4[3]) * c1;
    }
    delta8[(size_t)e * Hh + h] = 0.125f * (acc - qodd[qi * Hh + h] - kodd[ri * Hh + h]);
}

// ---------------- flash attention (round-6 config, reverted) ----------------
__global__ __launch_bounds__(64, 3) void flash5_k(
    const unsigned short* __restrict__ pQh, const unsigned short* __restrict__ pQl,
    const unsigned short* __restrict__ pKh, const unsigned short* __restrict__ pKl,
    const unsigned short* __restrict__ pVh, const unsigned short* __restrict__ pVl,
    const int* __restrict__ eid, const float* __restrict__ delta8,
    const float* __restrict__ koddT,
    float* __restrict__ Opart, float* __restrict__ Lpart)
{
    const int qt = blockIdx.x, h = blockIdx.y, s = blockIdx.z;
    const int L = threadIdx.x, quad = L >> 4, l15 = L & 15;
    const int q0 = qt * 16;
    __shared__ unsigned short phi[16][80];
    __shared__ unsigned short plo[16][80];

    bf16x8 qh[2], ql[2];
    #pragma unroll
    for (int kc = 0; kc < 2; ++kc) {
        size_t off = ((size_t)((h * 96 + qt) * 2 + kc)) * 512 + L * 8;
        qh[kc] = *(const bf16x8*)(pQh + off);
        ql[kc] = *(const bf16x8*)(pQl + off);
    }

    f32x4 O[4];
    float lsum[4];
    #pragma unroll
    for (int r = 0; r < 4; ++r) { lsum[r] = 0.f; O[r] = (f32x4){0.f, 0.f, 0.f, 0.f}; }

    const int NT = 24 / SPLITS;         // 6 r-tiles per split
    const int Tbase = s * NT;

    // ---- K frag double buffer: preload tile 0 ----
    bf16x8 kh0[4], kh1[4], kl0[4], kl1[4];
    {
        const int r0 = Tbase * 64;
        #pragma unroll
        for (int nt = 0; nt < 4; ++nt) {
            size_t b0 = ((size_t)((h * 96 + (r0 >> 4) + nt) * 2)) * 512 + L * 8;
            kh0[nt] = *(const bf16x8*)(pKh + b0);
            kh1[nt] = *(const bf16x8*)(pKh + b0 + 512);
            kl0[nt] = *(const bf16x8*)(pKl + b0);
            kl1[nt] = *(const bf16x8*)(pKl + b0 + 512);
        }
    }

    // ---- meta for tile 0 ----
    float kvcur[4], dcur[16];
    {
        const int r0 = Tbase * 64;
        int ecur[16];
        #pragma unroll
        for (int nt = 0; nt < 4; ++nt) {
            kvcur[nt] = koddT[h * Nn + r0 + nt * 16 + l15];
            #pragma unroll
            for (int reg = 0; reg < 4; ++reg)
                ecur[nt * 4 + reg] = eid[(size_t)(q0 + quad * 4 + reg) * Nn + r0 + nt * 16 + l15];
        }
        #pragma unroll
        for (int i = 0; i < 16; ++i) {
            int e = ecur[i];
            float d = delta8[(size_t)(e < 0 ? 0 : e) * Hh + h];
            dcur[i] = (e >= 0) ? d : 0.f;
        }
    }

    for (int T = 0; T < NT; ++T) {
        const int r0 = (Tbase + T) * 64;
        const bool more = (T + 1 < NT);

        int   enxt[16];
        float kvnxt[4];
        if (more) {
            const int r1 = r0 + 64;
            #pragma unroll
            for (int nt = 0; nt < 4; ++nt) {
                kvnxt[nt] = koddT[h * Nn + r1 + nt * 16 + l15];
                #pragma unroll
                for (int reg = 0; reg < 4; ++reg)
                    enxt[nt * 4 + reg] = eid[(size_t)(q0 + quad * 4 + reg) * Nn + r1 + nt * 16 + l15];
            }
        }

        bf16x8 vh0[4], vh1[4], vl0[4], vl1[4];
        #pragma unroll
        for (int dt = 0; dt < 4; ++dt) {
            size_t vb = ((size_t)((h * 48 + (r0 >> 5)) * 4 + dt)) * 512 + L * 8;
            vh0[dt] = *(const bf16x8*)(pVh + vb);
            vh1[dt] = *(const bf16x8*)(pVh + vb + 2048);
            vl0[dt] = *(const bf16x8*)(pVl + vb);
            vl1[dt] = *(const bf16x8*)(pVl + vb + 2048);
        }

        f32x4 S[4];
        #pragma unroll
        for (int nt = 0; nt < 4; ++nt) {
            f32x4 a = {0.f, 0.f, 0.f, 0.f};
            a = __builtin_amdgcn_mfma_f32_16x16x32_bf16(qh[0], kh0[nt], a, 0, 0, 0);
            a = __builtin_amdgcn_mfma_f32_16x16x32_bf16(qh[1], kh1[nt], a, 0, 0, 0);
            a = __builtin_amdgcn_mfma_f32_16x16x32_bf16(qh[0], kl0[nt], a, 0, 0, 0);
            a = __builtin_amdgcn_mfma_f32_16x16x32_bf16(qh[1], kl1[nt], a, 0, 0, 0);
            a = __builtin_amdgcn_mfma_f32_16x16x32_bf16(ql[0], kh0[nt], a, 0, 0, 0);
            a = __builtin_amdgcn_mfma_f32_16x16x32_bf16(ql[1], kh1[nt], a, 0, 0, 0);
            S[nt] = a;
        }

        if (more) {
            const int r1 = r0 + 64;
            #pragma unroll
            for (int nt = 0; nt < 4; ++nt) {
                size_t b0 = ((size_t)((h * 96 + (r1 >> 4) + nt) * 2)) * 512 + L * 8;
                kh0[nt] = *(const bf16x8*)(pKh + b0);
                kh1[nt] = *(const bf16x8*)(pKh + b0 + 512);
                kl0[nt] = *(const bf16x8*)(pKl + b0);
                kl1[nt] = *(const bf16x8*)(pKl + b0 + 512);
            }
        }

        #pragma unroll
        for (int reg = 0; reg < 4; ++reg) {
            float p[4];
            #pragma unroll
            for (int nt = 0; nt < 4; ++nt) {
                p[nt] = __expf(S[nt][reg] + kvcur[nt] + dcur[nt * 4 + reg] - M0);
                lsum[reg] += p[nt];
                unsigned short hi = bf16_rne(p[nt]);
                phi[quad * 4 + reg][nt * 16 + l15] = hi;
                plo[quad * 4 + reg][nt * 16 + l15] = bf16_rne(p[nt] - bf16_tof(hi));
            }
        }

        bf16x8 ph[2], pl[2];
        #pragma unroll
        for (int kc2 = 0; kc2 < 2; ++kc2) {
            ph[kc2] = *(const bf16x8*)&phi[l15][kc2 * 32 + quad * 8];
            pl[kc2] = *(const bf16x8*)&plo[l15][kc2 * 32 + quad * 8];
        }

        #pragma unroll
        for (int dt = 0; dt < 4; ++dt) {
            f32x4 a = O[dt];
            a = __builtin_amdgcn_mfma_f32_16x16x32_bf16(ph[0], vh0[dt], a, 0, 0, 0);
            a = __builtin_amdgcn_mfma_f32_16x16x32_bf16(ph[1], vh1[dt], a, 0, 0, 0);
            a = __builtin_amdgcn_mfma_f32_16x16x32_bf16(ph[0], vl0[dt], a, 0, 0, 0);
            a = __builtin_amdgcn_mfma_f32_16x16x32_bf16(ph[1], vl1[dt], a, 0, 0, 0);
            a = __builtin_amdgcn_mfma_f32_16x16x32_bf16(pl[0], vh0[dt], a, 0, 0, 0);
            a = __builtin_amdgcn_mfma_f32_16x16x32_bf16(pl[1], vh1[dt], a, 0, 0, 0);
            O[dt] = a;
        }

        if (more) {
            #pragma unroll
            for (int i = 0; i < 16; ++i) {
                int e = enxt[i];
                float d = delta8[(size_t)(e < 0 ? 0 : e) * Hh + h];
                dcur[i] = (e >= 0) ? d : 0.f;
            }
            #pragma unroll
            for (int nt = 0; nt < 4; ++nt) kvcur[nt] = kvnxt[nt];
        }
    }

    #pragma unroll
    for (int reg = 0; reg < 4; ++reg) {
        #pragma unroll
        for (int o = 1; o < 16; o <<= 1) lsum[reg] += __shfl_xor(lsum[reg], o);
    }

    #pragma unroll
    for (int dt = 0; dt < 4; ++dt)
        #pragma unroll
        for (int reg = 0; reg < 4; ++reg)
            Opart[((size_t)(s * Hh + h) * Nn + q0 + quad * 4 + reg) * 64 + dt * 16 + l15] = O[dt][reg];
    if (l15 == 0) {
        #pragma unroll
        for (int reg = 0; reg < 4; ++reg)
            Lpart[(size_t)(s * Hh + h) * Nn + q0 + quad * 4 + reg] = lsum[reg];
    }
}

// ------- split-K combine + maxpool via ordered-uint atomicMax (512 slots) ---
__global__ __launch_bounds__(256) void combine_mp_k(
    const float* __restrict__ Opart, const float* __restrict__ Lpart,
    unsigned* __restrict__ ordmax)
{
    const int b = blockIdx.x;
    const int t = threadIdx.x;
    const int cg = (t & 127) * 4;
    const int h = cg >> 6, d = cg & 63;
    const int rh = t >> 7;
    f4 mx = {-3.0e38f, -3.0e38f, -3.0e38f, -3.0e38f};
    for (int r = 0; r < 8; ++r) {
        int q = b * 16 + rh * 8 + r;
        float l = 0.f;
        f4 o = {0.f, 0.f, 0.f, 0.f};
        #pragma unroll
        for (int s2 = 0; s2 < SPLITS; ++s2) {
            l += Lpart[(size_t)(s2 * Hh + h) * Nn + q];
            f4 ov = *(const f4*)(Opart + ((size_t)(s2 * Hh + h) * Nn + q) * 64 + d);
            #pragma unroll
            for (int c = 0; c < 4; ++c) o[c] += ov[c];
        }
        float inv = 1.0f / l;
        #pragma unroll
        for (int c = 0; c < 4; ++c) mx[c] = fmaxf(mx[c], o[c] * inv);
    }
    #pragma unroll
    for (int c = 0; c < 4; ++c) atomicMax(&ordmax[cg + c], f2ord(mx[c]));
}

__global__ void decode_k(const unsigned* __restrict__ ordmax, float* __restrict__ outp)
{
    int t = blockIdx.x * 256 + threadIdx.x;
    if (t >= Dd) return;
    unsigned u = ordmax[t];
    outp[t] = (u & 0x80000000u) ? __uint_as_float(u ^ 0x80000000u) : __uint_as_float(~u);
}

// ---------------------------------------------------------------------------
extern "C" void kernel_launch(void* const* d_in, const int* in_sizes, int n_in,
                              void* d_out, int out_size, void* d_ws, size_t ws_size,
                              hipStream_t stream)
{
    const float* feat   = (const float*)d_in[0];
    const int*   rawidx = (const int*)d_in[1];
    const float* attr   = (const float*)d_in[2];
    const float* Wq = (const float*)d_in[4];
    const float* bq = (const float*)d_in[5];
    const float* Wk = (const float*)d_in[6];
    const float* bk = (const float*)d_in[7];
    const float* Wv = (const float*)d_in[8];
    const float* bv = (const float*)d_in[9];
    float* outp = (float*)d_out;
    const int E = in_sizes[2];

    const size_t ND_ = (size_t)Nn * Dd;            // 786432
    const size_t NN_ = (size_t)Nn * Nn;            // 2359296
    const size_t PK_ = (size_t)Hh * 96 * 2 * 512;  // 786432 bf16 per pack array
    // Prefix (dead by flash): Q + K + feat/W packs + rel = 5,505,024 f >= Opart
    // (SPLITS*Hh*Nn*64 = 3,145,728 f). eid onward stays live through flash.
    float* ws    = (float*)d_ws;
    float* Q     = ws;                    // 786432 f
    float* K     = Q + ND_;               // 786432 f
    unsigned short* pFh = (unsigned short*)(K + ND_);   // 4 x 786432 shorts
    unsigned short* pFl = pFh + PK_;
    unsigned short* pWh = pFl + PK_;
    unsigned short* pWl = pWh + PK_;
    float* rel   = (float*)(pWl + PK_);   // 2359296 f
    int*   eid   = (int*)(rel + NN_);     // 2359296 i  (live through flash)
    float* delta8 = (float*)(eid + NN_);  // E*Hh
    float* qodd  = delta8 + (size_t)E * Hh;
    float* kodd  = qodd + (size_t)Nn * Hh;
    float* koddT = kodd + (size_t)Nn * Hh;
    int*   idxn  = (int*)(koddT + (size_t)Nn * Hh);
    unsigned short* pQh = (unsigned short*)(idxn + 2 * E);
    unsigned short* pQl = pQh + PK_;
    unsigned short* pKh = pQl + PK_;
    unsigned short* pKl = pKh + PK_;
    unsigned short* pVh = pKl + PK_;
    unsigned short* pVl = pVh + PK_;
    float* Lpart = (float*)(pVl + PK_);                  // SPLITS*Hh*Nn
    unsigned* ordmax = (unsigned*)(Lpart + (size_t)SPLITS * Hh * Nn);  // 512
    float* Opart = ws;   // overlays prefix (all dead by flash time)

    pack_fw_k<<<dim3(384, 2), 256, 0, stream>>>(feat, Wq, Wk, Wv, pFh, pFl, pWh, pWl);
    qkvm_k<<<dim3(8, 24, 3), 256, 0, stream>>>(pFh, pFl, pWh, pWl, bq, bk, bv,
                                               Q, K, pQh, pQl, pKh, pKl, pVh, pVl);
    init_rel_k<<<(int)((NN_ / 4 + 255) / 256), 256, 0, stream>>>(rel, eid, ordmax);
    scatter_k<<<(E + 255) / 256, 256, 0, stream>>>(rawidx, attr, rel, eid, idxn, E);
    oddsum_k<<<(2 * Nn * Hh + 255) / 256, 256, 0, stream>>>(Q, K, qodd, kodd, koddT);
    delta_k<<<(E * Hh + 255) / 256, 256, 0, stream>>>(idxn, rel, Q, K, qodd, kodd, delta8, E);
    flash5_k<<<dim3(96, 8, SPLITS), 64, 0, stream>>>(pQh, pQl, pKh, pKl, pVh, pVl,
                                                     eid, delta8, koddT, Opart, Lpart);
    combine_mp_k<<<96, 256, 0, stream>>>(Opart, Lpart, ordmax);
    decode_k<<<(Dd + 255) / 256, 256, 0, stream>>>(ordmax, outp);
}